// Round 7
// baseline (62.295 us; speedup 1.0000x reference)
//
#include <hip/hip_runtime.h>

// CLAHE: B=32, C=3, H=W=512, GRID=8x8 -> TILE=64x64 (4096 px), NUM_BINS=256,
// CLIP_LIMIT=40 -> clip value = 640.
// d_ws layout: [0, 6.29MB) f32 LUTs (lut_idx = ((b*8+ty)*8+tx)*3 + c),
//              [6.29MB, +25.2MB) u8 quantized image v = clip(floor(img*255)).

#define NBINS  256
#define TILE   64
#define CH     3
#define HH     512
#define WW     512
#define CLIPV  640
#define PIXELS 4096   // per tile

#define LUTS_FLOATS (32 * 8 * 8 * 3 * NBINS)          // 1,572,864
#define V8_BYTES    ((size_t)32 * 3 * HH * WW)        // 25,165,824

// ---------------- Kernel 1: stripe histogram + clip + cumsum -> LUT ------------
// One block per (plane, tile-row): 96*8 = 768 blocks. Block reads its
// 64-row x 512-px stripe FULLY SEQUENTIALLY (4 KB/wave-instr), accumulates 8
// tile histograms in LDS, writes v8 linearly, then each wave scans 2 hists.
__global__ __launch_bounds__(256) void clahe_hist_lut_stripe(const float* __restrict__ img,
                                                             float* __restrict__ luts,
                                                             unsigned char* __restrict__ v8,
                                                             int write_v8) {
    const int t     = threadIdx.x;
    const int bid   = blockIdx.x;        // = plane*8 + ty
    const int ty    = bid & 7;
    const int plane = bid >> 3;          // b*3 + c
    const int c     = plane % 3;
    const int bb    = plane / 3;

    __shared__ unsigned int hist[8][NBINS];   // 8 KB
    #pragma unroll
    for (int h = 0; h < 8; ++h) hist[h][t] = 0u;
    __syncthreads();

    const size_t base = ((size_t)plane * HH + (size_t)ty * TILE) * WW;  // float offset
    const float4* __restrict__ src  = reinterpret_cast<const float4*>(img + base);
    uchar4*       __restrict__ dst8 = reinterpret_cast<uchar4*>(v8 + base);

    // stripe = 64 rows * 128 float4 = 8192 float4; 256 threads x 32 iters.
    #pragma unroll 4
    for (int it = 0; it < 32; ++it) {
        const int f = it * 256 + t;          // linear float4 index in stripe
        const float4 v = src[f];
        const int tile = (f & 127) >> 4;     // 4 px of a float4 share one tile
        atomicAdd(&hist[tile][min(max((int)floorf(v.x * 256.0f), 0), 255)], 1u);
        atomicAdd(&hist[tile][min(max((int)floorf(v.y * 256.0f), 0), 255)], 1u);
        atomicAdd(&hist[tile][min(max((int)floorf(v.z * 256.0f), 0), 255)], 1u);
        atomicAdd(&hist[tile][min(max((int)floorf(v.w * 256.0f), 0), 255)], 1u);
        if (write_v8) {
            uchar4 q;
            q.x = (unsigned char)min(max((int)floorf(v.x * 255.0f), 0), 255);
            q.y = (unsigned char)min(max((int)floorf(v.y * 255.0f), 0), 255);
            q.z = (unsigned char)min(max((int)floorf(v.z * 255.0f), 0), 255);
            q.w = (unsigned char)min(max((int)floorf(v.w * 255.0f), 0), 255);
            dst8[f] = q;
        }
    }
    __syncthreads();

    // Each of the 4 waves scans 2 histograms (256 bins = 4 chunks of 64, with
    // lane-shuffle inclusive scans and a serial carry). No block barriers.
    const int lane = t & 63;
    const int wid  = t >> 6;

    #pragma unroll
    for (int s = 0; s < 2; ++s) {
        const int h = wid * 2 + s;
        int carry = 0;
        int incl[4];
        #pragma unroll
        for (int ch = 0; ch < 4; ++ch) {
            int v = min((int)hist[h][ch * 64 + lane], CLIPV);
            #pragma unroll
            for (int off = 1; off < 64; off <<= 1) {
                int n = __shfl_up(v, off, 64);
                if (lane >= off) v += n;
            }
            incl[ch] = carry + v;
            carry += __shfl(v, 63, 64);      // chunk total from lane 63
        }
        const int total    = carry;
        const int excess   = PIXELS - total;           // >= 0
        const int residual = excess & 255;
        const int redist   = excess >> 8;
        const int job = ((bb * 8 + ty) * 8 + h) * 3 + c;
        float* __restrict__ dst = luts + (size_t)job * NBINS;
        #pragma unroll
        for (int ch = 0; ch < 4; ++ch) {
            const int bin = ch * 64 + lane;
            // inclusive cumsum of (clipped + redist + (bin<residual ? 1 : 0));
            // (nb-1)/pixels = 255/4096 exact in fp32; product <= 255 exact.
            const int cum = incl[ch] + redist * (bin + 1) + min(bin + 1, residual);
            dst[bin] = floorf(fminf((float)cum * (255.0f / 4096.0f), 255.0f));
        }
    }
}

// ---------------- Kernel 2: bilinear LUT application (band-staged, u32 pack) ---
// (byte-identical to R6 — A/B control)
// One block = 32 consecutive rows of one (b,c) plane. All 32-aligned row groups
// lie inside one "band" (rows sharing ty0/ty1: boundaries 32+64k and 480 are
// multiples of 32). Stage ONE u32 per (tx-pair, v):
//   Pack[tx][v] = L1[tx] | L1[tx+1]<<8 | L0[tx]<<16 | L0[tx+1]<<24
// (LUT entries are exact integers 0..255; L0 = L(ty0), L1 = L(ty1).)
// entry 7 duplicates (L7,L7); entry 8 = (L0-col0,L0-col0) serves the left edge,
// so wx needs no edge special-casing (duplicated pairs are wx-invariant).
// Per pixel: 1 ds_read_b32 + ubyte-unpack + 2 lerps. Exact f32 math.
template<bool USE_V8>
__global__ __launch_bounds__(256) void clahe_apply_band(const float* __restrict__ img,
                                                        const unsigned char* __restrict__ v8,
                                                        const float* __restrict__ luts,
                                                        float* __restrict__ out) {
    __shared__ unsigned int Pack[9][NBINS];   // 9 KB

    const int t     = threadIdx.x;
    const int bid   = blockIdx.x;
    const int g     = bid & 15;           // 32-row group 0..15
    const int plane = bid >> 4;           // b*3 + c, 0..95
    const int c     = plane % 3;
    const int bb    = plane / 3;
    const int y0    = g * 32;

    int ty0, ty1;
    if (y0 < 32)        { ty0 = 0; ty1 = 0; }
    else if (y0 >= 480) { ty0 = 7; ty1 = 7; }
    else                { ty0 = (y0 - 32) >> 6; ty1 = ty0 + 1; }

    const int rb0 = (bb * 8 + ty0) * 8;
    const int rb1 = (bb * 8 + ty1) * 8;

    // 16 coalesced 1KB loads (v = t); LUT values are integral 0..255.
    int iL0[8], iL1[8];
    #pragma unroll
    for (int tx = 0; tx < 8; ++tx) {
        iL0[tx] = (int)luts[((size_t)((rb0 + tx) * 3 + c)) * NBINS + t];
        iL1[tx] = (int)luts[((size_t)((rb1 + tx) * 3 + c)) * NBINS + t];
    }
    #pragma unroll
    for (int tx = 0; tx < 8; ++tx) {
        int txn = (tx < 7) ? tx + 1 : 7;
        Pack[tx][t] = (unsigned)(iL1[tx] | (iL1[txn] << 8) | (iL0[tx] << 16) | (iL0[txn] << 24));
    }
    Pack[8][t] = (unsigned)(iL1[0] | (iL1[0] << 8) | (iL0[0] << 16) | (iL0[0] << 24));
    __syncthreads();

    // thread covers 16 px at x0 (16-aligned: never crosses a blend breakpoint)
    const int x0     = (t & 31) * 16;
    const int tx_sel = (x0 < 32) ? 8 : ((x0 >= 480) ? 7 : ((x0 - 32) >> 6));
    const float c0f  = (float)(63 - ((x0 - 32) & 63));   // garbage at edges; harmless
    const unsigned int* __restrict__ Row = &Pack[tx_sel][0];
    const size_t pb = ((size_t)plane) << 18;

    #pragma unroll
    for (int j = 0; j < 4; ++j) {
        const int row = (t >> 5) + j * 8;
        const int y   = y0 + row;
        // On edge bands L0==L1 -> lerp slope 0 -> wy's value is irrelevant.
        const float wy = (float)(63 - ((y - 32) & 63)) * (1.0f / 63.0f);
        const size_t p = pb + (size_t)y * WW + x0;

        unsigned int w[4];
        float pix[16];
        if constexpr (USE_V8) {
            uint4 raw = *reinterpret_cast<const uint4*>(v8 + p);
            w[0] = raw.x; w[1] = raw.y; w[2] = raw.z; w[3] = raw.w;
        } else {
            #pragma unroll
            for (int q = 0; q < 4; ++q) {
                float4 f = *reinterpret_cast<const float4*>(img + p + q * 4);
                pix[q * 4 + 0] = f.x; pix[q * 4 + 1] = f.y;
                pix[q * 4 + 2] = f.z; pix[q * 4 + 3] = f.w;
            }
        }

        float res[16];
        #pragma unroll
        for (int q = 0; q < 4; ++q) {
            #pragma unroll
            for (int i2 = 0; i2 < 4; ++i2) {
                const int i = q * 4 + i2;
                int vv;
                if constexpr (USE_V8) vv = (w[q] >> (8 * i2)) & 255;
                else                  vv = min(max((int)floorf(pix[i] * 255.0f), 0), 255);
                const unsigned int raw = Row[vv];
                const float l1a = (float)(raw & 255u);           // v_cvt_f32_ubyte0
                const float l1b = (float)((raw >> 8) & 255u);    // v_cvt_f32_ubyte1
                const float l0a = (float)((raw >> 16) & 255u);   // v_cvt_f32_ubyte2
                const float l0b = (float)(raw >> 24);            // v_cvt_f32_ubyte3
                const float r0 = fmaf(wy, l0a - l1a, l1a);       // col tx0 value
                const float r1 = fmaf(wy, l0b - l1b, l1b);       // col tx1 value
                const float wx = (c0f - (float)i) * (1.0f / 63.0f);
                res[i] = fmaf(wx, r0 - r1, r1) * (1.0f / 255.0f);
            }
        }
        float4* o = reinterpret_cast<float4*>(out + p);
        o[0] = make_float4(res[0],  res[1],  res[2],  res[3]);
        o[1] = make_float4(res[4],  res[5],  res[6],  res[7]);
        o[2] = make_float4(res[8],  res[9],  res[10], res[11]);
        o[3] = make_float4(res[12], res[13], res[14], res[15]);
    }
}

extern "C" void kernel_launch(void* const* d_in, const int* in_sizes, int n_in,
                              void* d_out, int out_size, void* d_ws, size_t ws_size,
                              hipStream_t stream) {
    const float* img  = (const float*)d_in[0];
    float*       out  = (float*)d_out;
    float*       luts = (float*)d_ws;
    unsigned char* v8 = (unsigned char*)d_ws + (size_t)LUTS_FLOATS * 4;

    const bool use_v8 = ws_size >= (size_t)LUTS_FLOATS * 4 + V8_BYTES;

    // Kernel 1: one block per (plane, tile-row) stripe: 96*8 = 768 blocks
    clahe_hist_lut_stripe<<<768, 256, 0, stream>>>(img, luts, v8, use_v8 ? 1 : 0);
    // Kernel 2: one block per (plane, 32-row band group): 96 * 16 = 1536 blocks
    if (use_v8)
        clahe_apply_band<true><<<1536, 256, 0, stream>>>(img, v8, luts, out);
    else
        clahe_apply_band<false><<<1536, 256, 0, stream>>>(img, v8, luts, out);
}